// Round 9
// baseline (347.474 us; speedup 1.0000x reference)
//
#include <hip/hip_runtime.h>

#define HID 128
#define EPS 1e-5f
#define BSH 8                 // bucket = 256 dst nodes

typedef unsigned short ushort_t;
typedef unsigned int uint_t;
typedef short short8v __attribute__((ext_vector_type(8)));
typedef ushort_t ushort8v __attribute__((ext_vector_type(8)));
typedef float float4v __attribute__((ext_vector_type(4)));

__device__ __forceinline__ ushort_t f2bf_rne(float f) {
    unsigned u = __float_as_uint(f);
    unsigned r = u + 0x7fffu + ((u >> 16) & 1u);
    return (ushort_t)(r >> 16);
}
__device__ __forceinline__ float bf2f(ushort_t s) {
    return __uint_as_float(((unsigned)s) << 16);
}
__device__ __forceinline__ float bf2f_lo(uint_t u) {      // low bf16 of packed pair
    return __uint_as_float(u << 16);
}
__device__ __forceinline__ float bf2f_hi(uint_t u) {      // high bf16 of packed pair
    return __uint_as_float(u & 0xffff0000u);
}

// ---------------- bucketed CSR build ----------------

// coarse histogram of dst buckets (LDS-reduced)
__global__ void hist_kernel(const int* __restrict__ col, int E, int chunk,
                            int* __restrict__ bkthist, int nbkt) {
    __shared__ int lh[512];
    int tid = threadIdx.x;
    for (int i = tid; i < nbkt; i += 256) lh[i] = 0;
    __syncthreads();
    int base = blockIdx.x * chunk;
    int end = min(base + chunk, E);
    for (int e = base + tid; e < end; e += 256) atomicAdd(&lh[col[e] >> BSH], 1);
    __syncthreads();
    for (int i = tid; i < nbkt; i += 256) if (lh[i]) atomicAdd(&bkthist[i], lh[i]);
}

// single-block scan of bucket counts -> bktbase[nbkt+1], bktcur copy
__global__ void bktscan_kernel(const int* __restrict__ bkthist, int* __restrict__ bktbase,
                               int* __restrict__ bktcur, int nbkt) {
    __shared__ int sm[512];
    int t = threadIdx.x;
    int v = (t < nbkt) ? bkthist[t] : 0;
    sm[t] = v;
    __syncthreads();
    for (int off = 1; off < 512; off <<= 1) {
        int add = (t >= off) ? sm[t - off] : 0;
        __syncthreads();
        sm[t] += add;
        __syncthreads();
    }
    if (t < nbkt) {
        int ex = sm[t] - v;
        bktbase[t] = ex;
        bktcur[t] = ex;
    }
    if (t == 511) bktbase[nbkt] = sm[511];
}

// partition edges into bucket-contiguous packed (src | dstLow<<24); two sweeps per chunk
__global__ void part_kernel(const int* __restrict__ row, const int* __restrict__ col,
                            int* __restrict__ bktcur, uint_t* __restrict__ epart,
                            int E, int chunk, int nbkt) {
    __shared__ int lh[512];
    __shared__ int cur[512];
    int tid = threadIdx.x;
    for (int i = tid; i < nbkt; i += 256) lh[i] = 0;
    __syncthreads();
    int base = blockIdx.x * chunk;
    int end = min(base + chunk, E);
    for (int e = base + tid; e < end; e += 256) atomicAdd(&lh[col[e] >> BSH], 1);
    __syncthreads();
    for (int i = tid; i < nbkt; i += 256) {
        int c = lh[i];
        cur[i] = c ? atomicAdd(&bktcur[i], c) : 0;
    }
    __syncthreads();
    for (int e = base + tid; e < end; e += 256) {
        int d = col[e];
        int pos = atomicAdd(&cur[d >> BSH], 1);
        epart[pos] = (uint_t)row[e] | ((uint_t)(d & 255) << 24);
    }
}

// per-bucket degree count (LDS) -> cnt + dinv + gcnt, coalesced, no per-edge global atomics
__global__ void count_kernel(const uint_t* __restrict__ epart, const int* __restrict__ bktbase,
                             int* __restrict__ cnt, float* __restrict__ dinv,
                             const int* __restrict__ batch, int* __restrict__ gcnt, int N) {
    __shared__ int nc[256];
    int tid = threadIdx.x;
    int b = blockIdx.x;
    nc[tid] = 0;
    __syncthreads();
    int s = bktbase[b], e2 = bktbase[b + 1];
    for (int i = s + tid; i < e2; i += 256) atomicAdd(&nc[epart[i] >> 24], 1);
    __syncthreads();
    int n = (b << BSH) + tid;
    if (n < N) {
        cnt[n] = nc[tid];
        dinv[n] = rsqrtf((float)(nc[tid] + 1));
        atomicAdd(&gcnt[batch[n]], 1);
    }
}

// per-bucket CSR placement of packed {src, dinv[src]}; scattered writes in ~32KB window
__global__ void place_kernel(const uint_t* __restrict__ epart, const int* __restrict__ bktbase,
                             const int* __restrict__ colptr, const float* __restrict__ dinv,
                             int2* __restrict__ swsrcs) {
    __shared__ int nc[256];
    int tid = threadIdx.x;
    int b = blockIdx.x;
    nc[tid] = 0;
    __syncthreads();
    int s = bktbase[b], e2 = bktbase[b + 1];
    for (int i = s + tid; i < e2; i += 256) {
        uint_t pv = epart[i];
        int dl = pv >> 24;
        int d = (b << BSH) + dl;
        int src = (int)(pv & 0xFFFFFFu);
        int pos = atomicAdd(&nc[dl], 1);
        swsrcs[colptr[d] + pos] = make_int2(src, __float_as_int(dinv[src]));
    }
}

// inclusive scan per 1024-block; colptr[i+1] = partial, bsum[b] = block total
__global__ void scan1_kernel(const int* __restrict__ cnt, int* __restrict__ colptr,
                             int* __restrict__ bsum, int N) {
    __shared__ int sm[1024];
    int t = threadIdx.x;
    int i = blockIdx.x * 1024 + t;
    sm[t] = (i < N) ? cnt[i] : 0;
    __syncthreads();
    for (int off = 1; off < 1024; off <<= 1) {
        int add = (t >= off) ? sm[t - off] : 0;
        __syncthreads();
        sm[t] += add;
        __syncthreads();
    }
    if (i < N) colptr[i + 1] = sm[t];
    if (t == 1023) bsum[blockIdx.x] = sm[t];
}

__global__ void scan2_kernel(int* __restrict__ bsum, int nb) {
    __shared__ int sm[128];
    int t = threadIdx.x;
    int v = (t < nb) ? bsum[t] : 0;
    sm[t] = v;
    __syncthreads();
    for (int off = 1; off < 128; off <<= 1) {
        int add = (t >= off) ? sm[t - off] : 0;
        __syncthreads();
        sm[t] += add;
        __syncthreads();
    }
    if (t < nb) bsum[t] = sm[t] - v;   // exclusive
}

__global__ void scan3_kernel(int* __restrict__ colptr, const int* __restrict__ bsum, int N) {
    int i = blockIdx.x * blockDim.x + threadIdx.x;
    if (i < N) colptr[i + 1] += bsum[i >> 10];
    if (i == 0) colptr[0] = 0;
}

// ---------------- layer 1: wave-cooperative x aggregation (6 ch) ----------------

__global__ __launch_bounds__(256) void aggx_kernel(
    const float* __restrict__ x, const float* __restrict__ dinv,
    const int* __restrict__ colptr, const int2* __restrict__ swsrcs,
    float* __restrict__ aggx, int N) {
    int tid = threadIdx.x;
    int g = tid >> 3;        // group 0..31 within block (one node each)
    int l = tid & 7;         // lane in group; lanes 0-5 carry channels
    int n = blockIdx.x * 32 + g;
    if (n >= N) return;
    float dn = dinv[n];
    float acc = (l < 6) ? x[(size_t)n * 6 + l] * dn * dn : 0.f;
    int s0 = colptr[n], s1 = colptr[n + 1];
    for (int j = s0; j < s1; j += 4) {
        int2 sv[4];
#pragma unroll
        for (int u = 0; u < 4; u++) {
            int idx = (j + u < s1) ? (j + u) : (s1 - 1);
            sv[u] = swsrcs[idx];
        }
        float xv[4];
#pragma unroll
        for (int u = 0; u < 4; u++)
            xv[u] = (l < 6) ? x[(size_t)sv[u].x * 6 + l] : 0.f;
#pragma unroll
        for (int u = 0; u < 4; u++) {
            float w = (j + u < s1) ? __int_as_float(sv[u].y) * dn : 0.f;
            acc += xv[u] * w;
        }
    }
    if (l < 6) aggx[(size_t)n * 6 + l] = acc;
}

__global__ void gemm1_kernel(const float* __restrict__ aggx, const float* __restrict__ W1,
                             const float* __restrict__ b1, const float* __restrict__ g1,
                             const float* __restrict__ be1, const float* __restrict__ m1,
                             const float* __restrict__ v1, ushort_t* __restrict__ h, int N) {
    int ln = threadIdx.x >> 7;     // 0..1 (2 nodes per 256-block)
    int c  = threadIdx.x & 127;
    int n  = blockIdx.x * 2 + ln;
    if (n >= N) return;
    float acc = 0.f;
#pragma unroll
    for (int k = 0; k < 6; k++) acc += aggx[(size_t)n * 6 + k] * W1[k * HID + c];
    float s = rsqrtf(v1[c] + EPS);
    float A = g1[c] * s;
    float C = (b1[c] - m1[c]) * A + be1[c];
    float r = acc * A + C;
    h[(size_t)n * HID + c] = f2bf_rne(r > 0.f ? r : 0.f);
}

// ---------------- 128-wide aggregation: half-wave split gather ----------------
// One wave per node. 32 lanes x uint2 (8B) cover a 256B bf16 row; the two
// half-waves process interleaved edges (half h takes edges j+2u+h).
// Main loop: 16 edges/iter -> 8 x 8B loads in flight per lane (4KB/wave).
// Tail: unmasked-8 then masked-8. Cross-half reduce via shfl_xor(32).

__global__ __launch_bounds__(256) void agg_kernel(
    const ushort_t* __restrict__ h, const float* __restrict__ dinv,
    const int* __restrict__ colptr, const int2* __restrict__ swsrcs,
    ushort_t* __restrict__ aggb, int N) {
    int wid  = threadIdx.x >> 6;          // 4 nodes per 256-block
    int lane = threadIdx.x & 63;
    int half = lane >> 5;                 // 0 or 1
    int l32  = lane & 31;                 // uint2 index within 256B row
    int n = blockIdx.x * 4 + wid;
    if (n >= N) return;
    float dn = dinv[n];
    const uint2* hv = (const uint2*)h;    // row = 32 uint2
    float a0 = 0.f, a1 = 0.f, a2 = 0.f, a3 = 0.f;
    if (half == 0) {                      // self term in half 0 only
        uint2 hs = hv[(size_t)n * 32 + l32];
        float sw = dn * dn;
        a0 = bf2f_lo(hs.x) * sw; a1 = bf2f_hi(hs.x) * sw;
        a2 = bf2f_lo(hs.y) * sw; a3 = bf2f_hi(hs.y) * sw;
    }
    int s0 = colptr[n], s1 = colptr[n + 1];
    int j = s0;
    for (; j + 16 <= s1; j += 16) {       // 16 edges/iter, 8 per half, unmasked
        int2 sv[8];
#pragma unroll
        for (int u = 0; u < 8; u++) sv[u] = swsrcs[j + 2 * u + half];
        uint2 hh[8];
#pragma unroll
        for (int u = 0; u < 8; u++) hh[u] = hv[(size_t)sv[u].x * 32 + l32];
#pragma unroll
        for (int u = 0; u < 8; u++) {
            float w = __int_as_float(sv[u].y) * dn;
            a0 += bf2f_lo(hh[u].x) * w; a1 += bf2f_hi(hh[u].x) * w;
            a2 += bf2f_lo(hh[u].y) * w; a3 += bf2f_hi(hh[u].y) * w;
        }
    }
    if (j + 8 <= s1) {                    // 8 edges, 4 per half, unmasked
        int2 sv[4];
#pragma unroll
        for (int u = 0; u < 4; u++) sv[u] = swsrcs[j + 2 * u + half];
        uint2 hh[4];
#pragma unroll
        for (int u = 0; u < 4; u++) hh[u] = hv[(size_t)sv[u].x * 32 + l32];
#pragma unroll
        for (int u = 0; u < 4; u++) {
            float w = __int_as_float(sv[u].y) * dn;
            a0 += bf2f_lo(hh[u].x) * w; a1 += bf2f_hi(hh[u].x) * w;
            a2 += bf2f_lo(hh[u].y) * w; a3 += bf2f_hi(hh[u].y) * w;
        }
        j += 8;
    }
    if (j < s1) {                         // masked final 8-group, 4 per half
        int2 sv[4];
#pragma unroll
        for (int u = 0; u < 4; u++) {
            int e = j + 2 * u + half;
            sv[u] = swsrcs[(e < s1) ? e : (s1 - 1)];
        }
        uint2 hh[4];
#pragma unroll
        for (int u = 0; u < 4; u++) hh[u] = hv[(size_t)sv[u].x * 32 + l32];
#pragma unroll
        for (int u = 0; u < 4; u++) {
            float w = (j + 2 * u + half < s1) ? __int_as_float(sv[u].y) * dn : 0.f;
            a0 += bf2f_lo(hh[u].x) * w; a1 += bf2f_hi(hh[u].x) * w;
            a2 += bf2f_lo(hh[u].y) * w; a3 += bf2f_hi(hh[u].y) * w;
        }
    }
    // cross-half reduction (lane l <-> l+32)
    a0 += __shfl_xor(a0, 32);
    a1 += __shfl_xor(a1, 32);
    a2 += __shfl_xor(a2, 32);
    a3 += __shfl_xor(a3, 32);
    if (half == 0) {
        uint2 o;
        o.x = (uint_t)f2bf_rne(a0) | ((uint_t)f2bf_rne(a1) << 16);
        o.y = (uint_t)f2bf_rne(a2) | ((uint_t)f2bf_rne(a3) << 16);
        ((uint2*)aggb)[(size_t)n * 32 + l32] = o;
    }
}

// ---------------- W pre-split: f32 [in][out] -> swizzled bf16 hi||lo (both layers) ----------------

__global__ void wprep_kernel(const float* __restrict__ W2, const float* __restrict__ W3,
                             ushort_t* __restrict__ Wsw2, ushort_t* __restrict__ Wsw3) {
    int bb = blockIdx.x;
    const float* W = (bb < 64) ? W2 : W3;
    ushort_t* Wsw = (bb < 64) ? Wsw2 : Wsw3;
    int idx = (bb & 63) * 256 + threadIdx.x;    // 64 blocks x 256 = 16384 per layer
    int k = idx >> 7;        // in
    int o = idx & 127;       // out
    float w = W[idx];        // W[k][o]
    unsigned u = __float_as_uint(w);
    ushort_t hw = (ushort_t)(u >> 16);                       // truncated bf16 (hi)
    float hf = __uint_as_float(u & 0xffff0000u);
    float lo = w - hf;
    ushort_t lw = (ushort_t)(__float_as_uint(lo) >> 16);     // truncated bf16 (lo)
    int chunk = k >> 3, j = k & 7;
    int sidx = o * 128 + ((chunk ^ (o & 7)) << 3) + j;
    Wsw[sidx] = hw;
    Wsw[16384 + sidx] = lw;
}

// ---------------- BN coef precompute (both layers) ----------------

__global__ void bnprep_kernel(const float* __restrict__ b2, const float* __restrict__ g2,
                              const float* __restrict__ be2, const float* __restrict__ m2,
                              const float* __restrict__ v2, float* __restrict__ cA2,
                              float* __restrict__ cC2,
                              const float* __restrict__ b3, const float* __restrict__ g3,
                              const float* __restrict__ be3, const float* __restrict__ m3,
                              const float* __restrict__ v3, float* __restrict__ cA3,
                              float* __restrict__ cC3) {
    int c = threadIdx.x;
    const float* b = blockIdx.x ? b3 : b2;
    const float* g = blockIdx.x ? g3 : g2;
    const float* be = blockIdx.x ? be3 : be2;
    const float* m = blockIdx.x ? m3 : m2;
    const float* v = blockIdx.x ? v3 : v2;
    float* cA = blockIdx.x ? cA3 : cA2;
    float* cC = blockIdx.x ? cC3 : cC2;
    float A = g[c] * rsqrtf(v[c] + EPS);
    cA[c] = A;
    cC[c] = (b[c] - m[c]) * A + be[c];
}

// ---------------- MFMA GEMM: bf16 A x (Wh+Wl) + BN + ReLU (+ fused pool) ----------------

template <bool POOL>
__global__ __launch_bounds__(256, 2) void gemm_mfma_kernel(
    const ushort_t* __restrict__ aggb,    // [N][128] bf16
    const ushort_t* __restrict__ Wsw,     // swizzled hi||lo, 64 KB
    const float* __restrict__ cA,         // [128] BN scale
    const float* __restrict__ cC,         // [128] BN shift
    ushort_t* __restrict__ out_h,         // non-pool: bf16 h out
    float* __restrict__ out_pool,         // pool: f32 accum out
    const int* __restrict__ batch, int N) {
    __shared__ unsigned smu[16384];       // 64 KB: W(hi|lo) during K-loop, f32 tile in epilogue
    ushort_t* Wh = (ushort_t*)smu;
    ushort_t* Wl = (ushort_t*)smu + 16384;
    float* At = (float*)smu;

    int tid  = threadIdx.x;
    int wid  = tid >> 6;           // wave 0..3
    int lane = tid & 63;
    int l15  = lane & 15;
    int lg   = lane >> 4;          // 0..3

    int nbase = blockIdx.x * 128;
    int rbase = nbase + wid * 32;
    int r0c = min(rbase + l15, N - 1);
    int r1c = min(rbase + 16 + l15, N - 1);

    // BN coefs for this lane's 8 output channels (prefetch early)
    float kA[8], kC[8];
#pragma unroll
    for (int cb = 0; cb < 8; cb++) {
        int n = cb * 16 + l15;
        kA[cb] = cA[n];
        kC[cb] = cC[n];
    }

    // stage W into LDS (linear copy, layout pre-swizzled in global)
    {
        const float4* gsrc = (const float4*)Wsw;
        float4* ldst = (float4*)smu;
#pragma unroll
        for (int i = 0; i < 16; i++) ldst[i * 256 + tid] = gsrc[i * 256 + tid];
    }
    __syncthreads();

    float4v acc[2][8];
#pragma unroll
    for (int h = 0; h < 2; h++)
#pragma unroll
        for (int cb = 0; cb < 8; cb++) acc[h][cb] = (float4v){0.f, 0.f, 0.f, 0.f};

#pragma unroll
    for (int kk = 0; kk < 4; kk++) {
        int ko = kk * 32 + lg * 8;             // 8 consecutive k per lane
        short8v Ah0 = *(const short8v*)(aggb + (size_t)r0c * HID + ko);
        short8v Ah1 = *(const short8v*)(aggb + (size_t)r1c * HID + ko);
        int chunk = kk * 4 + lg;
#pragma unroll
        for (int cb = 0; cb < 8; cb++) {
            int n = cb * 16 + l15;
            int sidx = n * 128 + ((chunk ^ (n & 7)) << 3);
            short8v bh = *(const short8v*)(Wh + sidx);
            short8v bl = *(const short8v*)(Wl + sidx);
            acc[0][cb] = __builtin_amdgcn_mfma_f32_16x16x32_bf16(Ah0, bh, acc[0][cb], 0, 0, 0);
            acc[1][cb] = __builtin_amdgcn_mfma_f32_16x16x32_bf16(Ah1, bh, acc[1][cb], 0, 0, 0);
            acc[0][cb] = __builtin_amdgcn_mfma_f32_16x16x32_bf16(Ah0, bl, acc[0][cb], 0, 0, 0);
            acc[1][cb] = __builtin_amdgcn_mfma_f32_16x16x32_bf16(Ah1, bl, acc[1][cb], 0, 0, 0);
        }
    }

    __syncthreads();   // all waves done reading W; reuse LDS as f32 tile

    // BN + ReLU, write acc into LDS tile [128][128] with col swizzle
#pragma unroll
    for (int h = 0; h < 2; h++) {
#pragma unroll
        for (int r = 0; r < 4; r++) {
            int lr = wid * 32 + h * 16 + lg * 4 + r;
            int swz = ((lr >> 2) & 3) << 2;
#pragma unroll
            for (int cb = 0; cb < 8; cb++) {
                int c = cb * 16 + l15;
                float val = fmaxf(acc[h][cb][r] * kA[cb] + kC[cb], 0.f);
                if (POOL && (nbase + lr) >= N) val = 0.f;
                At[lr * 128 + (c ^ swz)] = val;
            }
        }
    }
    __syncthreads();

    if (!POOL) {
        // coalesced bf16 row writes: 16 threads x 8ch cover a 256B row
        int c8 = tid & 15;           // 8-channel chunk
        int rb = tid >> 4;           // 16 rows per pass
#pragma unroll
        for (int i = 0; i < 8; i++) {
            int r = rb + i * 16;
            int gr = nbase + r;
            if (gr < N) {
                int swz = ((r >> 2) & 3) << 2;
                float4 va = *(float4*)&At[r * 128 + ((c8 * 8) ^ swz)];
                float4 vb = *(float4*)&At[r * 128 + ((c8 * 8 + 4) ^ swz)];
                ushort8v o;
                o[0] = f2bf_rne(va.x); o[1] = f2bf_rne(va.y);
                o[2] = f2bf_rne(va.z); o[3] = f2bf_rne(va.w);
                o[4] = f2bf_rne(vb.x); o[5] = f2bf_rne(vb.y);
                o[6] = f2bf_rne(vb.z); o[7] = f2bf_rne(vb.w);
                *(ushort8v*)&out_h[(size_t)gr * HID + c8 * 8] = o;
            }
        }
    } else {
        // segmented pool reduction: batch is sorted, few segments per block
        int c  = tid & 127;
        int rh = tid >> 7;          // 0..1, rows rh*64 .. rh*64+63
        int r0 = rh * 64;
        int cg = batch[min(nbase + r0, N - 1)];
        float racc = 0.f;
        for (int r = r0; r < r0 + 64; r++) {
            int gr = min(nbase + r, N - 1);
            int g = batch[gr];
            float vv = At[r * 128 + (c ^ (((r >> 2) & 3) << 2))];
            if (g != cg) {
                atomicAdd(&out_pool[(size_t)cg * HID + c], racc);
                racc = 0.f;
                cg = g;
            }
            racc += vv;
        }
        atomicAdd(&out_pool[(size_t)cg * HID + c], racc);
    }
}

// ---------------- pooling finalize ----------------

__global__ void finalize_kernel(float* __restrict__ out, const int* __restrict__ gcnt, int total) {
    int i = blockIdx.x * blockDim.x + threadIdx.x;
    if (i < total) {
        int gidx = i >> 7;
        out[i] = out[i] / fmaxf((float)gcnt[gidx], 1.f);
    }
}

// ---------------- launch ----------------

extern "C" void kernel_launch(void* const* d_in, const int* in_sizes, int n_in,
                              void* d_out, int out_size, void* d_ws, size_t ws_size,
                              hipStream_t stream) {
    const float* x   = (const float*)d_in[0];
    const int*  ei   = (const int*)d_in[1];
    const int*  batch= (const int*)d_in[3];
    const float* W1  = (const float*)d_in[4];
    const float* b1  = (const float*)d_in[5];
    const float* W2  = (const float*)d_in[6];
    const float* b2  = (const float*)d_in[7];
    const float* W3  = (const float*)d_in[8];
    const float* b3  = (const float*)d_in[9];
    const float* g1  = (const float*)d_in[10];
    const float* be1 = (const float*)d_in[11];
    const float* m1  = (const float*)d_in[12];
    const float* v1  = (const float*)d_in[13];
    const float* g2  = (const float*)d_in[14];
    const float* be2 = (const float*)d_in[15];
    const float* m2  = (const float*)d_in[16];
    const float* v2  = (const float*)d_in[17];
    const float* g3  = (const float*)d_in[18];
    const float* be3 = (const float*)d_in[19];
    const float* m3  = (const float*)d_in[20];
    const float* v3  = (const float*)d_in[21];

    const int N  = in_sizes[0] / 6;
    const int E  = in_sizes[1] / 2;
    const int NG = out_size / HID;
    const int* row = ei;
    const int* col = ei + E;
    const int NBKT = (N + 255) >> BSH;        // 391 for N=100000 (<=512 supported)

    char* wp = (char*)d_ws;
    auto alloc = [&](size_t bytes) -> void* {
        void* p = (void*)wp;
        wp += (bytes + 255) & ~(size_t)255;
        return p;
    };
    float* dinv    = (float*)alloc((size_t)N * 4);
    int*   cnt     = (int*)alloc((size_t)N * 4);
    int*   colptr  = (int*)alloc(((size_t)N + 1) * 4);
    const int NB1 = (N + 1023) / 1024;
    int*   bsum    = (int*)alloc((size_t)NB1 * 4);
    int*   bkthist = (int*)alloc((size_t)(NBKT + 1) * 4);
    int*   bktbase = (int*)alloc((size_t)(NBKT + 1) * 4);
    int*   bktcur  = (int*)alloc((size_t)(NBKT + 1) * 4);
    uint_t* epart  = (uint_t*)alloc((size_t)E * 4);
    int2*  swsrcs  = (int2*)alloc((size_t)E * 8);
    float* aggx    = (float*)alloc((size_t)N * 6 * 4);
    ushort_t* aggb = (ushort_t*)alloc((size_t)N * HID * 2);
    ushort_t* h    = (ushort_t*)alloc((size_t)N * HID * 2);
    int*   gcnt    = (int*)alloc((size_t)NG * 4);
    ushort_t* Wsw2 = (ushort_t*)alloc((size_t)2 * HID * HID * 2);
    ushort_t* Wsw3 = (ushort_t*)alloc((size_t)2 * HID * HID * 2);
    float* cA2 = (float*)alloc(HID * 4);
    float* cC2 = (float*)alloc(HID * 4);
    float* cA3 = (float*)alloc(HID * 4);
    float* cC3 = (float*)alloc(HID * 4);
    float* outf   = (float*)d_out;

    hipMemsetAsync(bkthist, 0, (size_t)(NBKT + 1) * 4, stream);
    hipMemsetAsync(gcnt, 0, (size_t)NG * 4, stream);
    hipMemsetAsync(d_out, 0, (size_t)out_size * 4, stream);

    const int B = 256;
    // weight/BN precompute (tiny)
    wprep_kernel<<<128, 256, 0, stream>>>(W2, W3, Wsw2, Wsw3);
    bnprep_kernel<<<2, 128, 0, stream>>>(b2, g2, be2, m2, v2, cA2, cC2,
                                         b3, g3, be3, m3, v3, cA3, cC3);

    // bucketed CSR build
    const int HB = 512;
    const int hchunk = (E + HB - 1) / HB;
    hist_kernel<<<HB, B, 0, stream>>>(col, E, hchunk, bkthist, NBKT);
    bktscan_kernel<<<1, 512, 0, stream>>>(bkthist, bktbase, bktcur, NBKT);
    const int PB = 256;
    const int pchunk = (E + PB - 1) / PB;
    part_kernel<<<PB, B, 0, stream>>>(row, col, bktcur, epart, E, pchunk, NBKT);
    count_kernel<<<NBKT, B, 0, stream>>>(epart, bktbase, cnt, dinv, batch, gcnt, N);
    scan1_kernel<<<NB1, 1024, 0, stream>>>(cnt, colptr, bsum, N);
    scan2_kernel<<<1, 128, 0, stream>>>(bsum, NB1);
    scan3_kernel<<<(N + B - 1) / B, B, 0, stream>>>(colptr, bsum, N);
    place_kernel<<<NBKT, B, 0, stream>>>(epart, bktbase, colptr, dinv, swsrcs);

    // layer 1 (aggregate x first: only 6 channels)
    aggx_kernel<<<(N + 31) / 32, B, 0, stream>>>(x, dinv, colptr, swsrcs, aggx, N);
    gemm1_kernel<<<(N + 1) / 2, B, 0, stream>>>(aggx, W1, b1, g1, be1, m1, v1, h, N);

    const int NBLK = (N + 127) / 128;
    // layer 2
    agg_kernel<<<(N + 3) / 4, B, 0, stream>>>(h, dinv, colptr, swsrcs, aggb, N);
    gemm_mfma_kernel<false><<<NBLK, 256, 0, stream>>>(aggb, Wsw2, cA2, cC2, h, nullptr, nullptr, N);

    // layer 3 (+ fused mean-pool accumulate)
    agg_kernel<<<(N + 3) / 4, B, 0, stream>>>(h, dinv, colptr, swsrcs, aggb, N);
    gemm_mfma_kernel<true><<<NBLK, 256, 0, stream>>>(aggb, Wsw3, cA3, cC3, nullptr, outf, batch, N);

    finalize_kernel<<<(NG * HID + B - 1) / B, B, 0, stream>>>(outf, gcnt, NG * HID);
}

// Round 10
// 328.491 us; speedup vs baseline: 1.0578x; 1.0578x over previous
//
#include <hip/hip_runtime.h>

#define HID 128
#define EPS 1e-5f
#define BSH 8                 // bucket = 256 dst nodes

typedef unsigned short ushort_t;
typedef unsigned int uint_t;
typedef short short8v __attribute__((ext_vector_type(8)));
typedef ushort_t ushort8v __attribute__((ext_vector_type(8)));
typedef float float4v __attribute__((ext_vector_type(4)));

__device__ __forceinline__ ushort_t f2bf_rne(float f) {
    unsigned u = __float_as_uint(f);
    unsigned r = u + 0x7fffu + ((u >> 16) & 1u);
    return (ushort_t)(r >> 16);
}
__device__ __forceinline__ float bf2f(ushort_t s) {
    return __uint_as_float(((unsigned)s) << 16);
}
__device__ __forceinline__ float bf2f_lo(uint_t u) {      // low bf16 of packed pair
    return __uint_as_float(u << 16);
}
__device__ __forceinline__ float bf2f_hi(uint_t u) {      // high bf16 of packed pair
    return __uint_as_float(u & 0xffff0000u);
}

// direct global->LDS DMA, 16B per lane (gfx950)
__device__ __forceinline__ void gload_lds16(const void* g, void* l) {
    __builtin_amdgcn_global_load_lds(
        (const __attribute__((address_space(1))) void*)g,
        (__attribute__((address_space(3))) void*)l, 16, 0, 0);
}

// ---------------- bucketed CSR build ----------------

// coarse histogram of dst buckets (LDS-reduced)
__global__ void hist_kernel(const int* __restrict__ col, int E, int chunk,
                            int* __restrict__ bkthist, int nbkt) {
    __shared__ int lh[512];
    int tid = threadIdx.x;
    for (int i = tid; i < nbkt; i += 256) lh[i] = 0;
    __syncthreads();
    int base = blockIdx.x * chunk;
    int end = min(base + chunk, E);
    for (int e = base + tid; e < end; e += 256) atomicAdd(&lh[col[e] >> BSH], 1);
    __syncthreads();
    for (int i = tid; i < nbkt; i += 256) if (lh[i]) atomicAdd(&bkthist[i], lh[i]);
}

// single-block scan of bucket counts -> bktbase[nbkt+1], bktcur copy
__global__ void bktscan_kernel(const int* __restrict__ bkthist, int* __restrict__ bktbase,
                               int* __restrict__ bktcur, int nbkt) {
    __shared__ int sm[512];
    int t = threadIdx.x;
    int v = (t < nbkt) ? bkthist[t] : 0;
    sm[t] = v;
    __syncthreads();
    for (int off = 1; off < 512; off <<= 1) {
        int add = (t >= off) ? sm[t - off] : 0;
        __syncthreads();
        sm[t] += add;
        __syncthreads();
    }
    if (t < nbkt) {
        int ex = sm[t] - v;
        bktbase[t] = ex;
        bktcur[t] = ex;
    }
    if (t == 511) bktbase[nbkt] = sm[511];
}

// partition edges into bucket-contiguous packed (src | dstLow<<24); two sweeps per chunk
__global__ void part_kernel(const int* __restrict__ row, const int* __restrict__ col,
                            int* __restrict__ bktcur, uint_t* __restrict__ epart,
                            int E, int chunk, int nbkt) {
    __shared__ int lh[512];
    __shared__ int cur[512];
    int tid = threadIdx.x;
    for (int i = tid; i < nbkt; i += 256) lh[i] = 0;
    __syncthreads();
    int base = blockIdx.x * chunk;
    int end = min(base + chunk, E);
    for (int e = base + tid; e < end; e += 256) atomicAdd(&lh[col[e] >> BSH], 1);
    __syncthreads();
    for (int i = tid; i < nbkt; i += 256) {
        int c = lh[i];
        cur[i] = c ? atomicAdd(&bktcur[i], c) : 0;
    }
    __syncthreads();
    for (int e = base + tid; e < end; e += 256) {
        int d = col[e];
        int pos = atomicAdd(&cur[d >> BSH], 1);
        epart[pos] = (uint_t)row[e] | ((uint_t)(d & 255) << 24);
    }
}

// per-bucket degree count (LDS) -> cnt + dinv + gcnt, coalesced, no per-edge global atomics
__global__ void count_kernel(const uint_t* __restrict__ epart, const int* __restrict__ bktbase,
                             int* __restrict__ cnt, float* __restrict__ dinv,
                             const int* __restrict__ batch, int* __restrict__ gcnt, int N) {
    __shared__ int nc[256];
    int tid = threadIdx.x;
    int b = blockIdx.x;
    nc[tid] = 0;
    __syncthreads();
    int s = bktbase[b], e2 = bktbase[b + 1];
    for (int i = s + tid; i < e2; i += 256) atomicAdd(&nc[epart[i] >> 24], 1);
    __syncthreads();
    int n = (b << BSH) + tid;
    if (n < N) {
        cnt[n] = nc[tid];
        dinv[n] = rsqrtf((float)(nc[tid] + 1));
        atomicAdd(&gcnt[batch[n]], 1);
    }
}

// per-bucket CSR placement of packed {src, dinv[src]}; scattered writes in ~32KB window
__global__ void place_kernel(const uint_t* __restrict__ epart, const int* __restrict__ bktbase,
                             const int* __restrict__ colptr, const float* __restrict__ dinv,
                             int2* __restrict__ swsrcs) {
    __shared__ int nc[256];
    int tid = threadIdx.x;
    int b = blockIdx.x;
    nc[tid] = 0;
    __syncthreads();
    int s = bktbase[b], e2 = bktbase[b + 1];
    for (int i = s + tid; i < e2; i += 256) {
        uint_t pv = epart[i];
        int dl = pv >> 24;
        int d = (b << BSH) + dl;
        int src = (int)(pv & 0xFFFFFFu);
        int pos = atomicAdd(&nc[dl], 1);
        swsrcs[colptr[d] + pos] = make_int2(src, __float_as_int(dinv[src]));
    }
}

// inclusive scan per 1024-block; colptr[i+1] = partial, bsum[b] = block total
__global__ void scan1_kernel(const int* __restrict__ cnt, int* __restrict__ colptr,
                             int* __restrict__ bsum, int N) {
    __shared__ int sm[1024];
    int t = threadIdx.x;
    int i = blockIdx.x * 1024 + t;
    sm[t] = (i < N) ? cnt[i] : 0;
    __syncthreads();
    for (int off = 1; off < 1024; off <<= 1) {
        int add = (t >= off) ? sm[t - off] : 0;
        __syncthreads();
        sm[t] += add;
        __syncthreads();
    }
    if (i < N) colptr[i + 1] = sm[t];
    if (t == 1023) bsum[blockIdx.x] = sm[t];
}

__global__ void scan2_kernel(int* __restrict__ bsum, int nb) {
    __shared__ int sm[128];
    int t = threadIdx.x;
    int v = (t < nb) ? bsum[t] : 0;
    sm[t] = v;
    __syncthreads();
    for (int off = 1; off < 128; off <<= 1) {
        int add = (t >= off) ? sm[t - off] : 0;
        __syncthreads();
        sm[t] += add;
        __syncthreads();
    }
    if (t < nb) bsum[t] = sm[t] - v;   // exclusive
}

__global__ void scan3_kernel(int* __restrict__ colptr, const int* __restrict__ bsum, int N) {
    int i = blockIdx.x * blockDim.x + threadIdx.x;
    if (i < N) colptr[i + 1] += bsum[i >> 10];
    if (i == 0) colptr[0] = 0;
}

// ---------------- layer 1: wave-cooperative x aggregation (6 ch) ----------------

__global__ __launch_bounds__(256) void aggx_kernel(
    const float* __restrict__ x, const float* __restrict__ dinv,
    const int* __restrict__ colptr, const int2* __restrict__ swsrcs,
    float* __restrict__ aggx, int N) {
    int tid = threadIdx.x;
    int g = tid >> 3;        // group 0..31 within block (one node each)
    int l = tid & 7;         // lane in group; lanes 0-5 carry channels
    int n = blockIdx.x * 32 + g;
    if (n >= N) return;
    float dn = dinv[n];
    float acc = (l < 6) ? x[(size_t)n * 6 + l] * dn * dn : 0.f;
    int s0 = colptr[n], s1 = colptr[n + 1];
    for (int j = s0; j < s1; j += 4) {
        int2 sv[4];
#pragma unroll
        for (int u = 0; u < 4; u++) {
            int idx = (j + u < s1) ? (j + u) : (s1 - 1);
            sv[u] = swsrcs[idx];
        }
        float xv[4];
#pragma unroll
        for (int u = 0; u < 4; u++)
            xv[u] = (l < 6) ? x[(size_t)sv[u].x * 6 + l] : 0.f;
#pragma unroll
        for (int u = 0; u < 4; u++) {
            float w = (j + u < s1) ? __int_as_float(sv[u].y) * dn : 0.f;
            acc += xv[u] * w;
        }
    }
    if (l < 6) aggx[(size_t)n * 6 + l] = acc;
}

__global__ void gemm1_kernel(const float* __restrict__ aggx, const float* __restrict__ W1,
                             const float* __restrict__ b1, const float* __restrict__ g1,
                             const float* __restrict__ be1, const float* __restrict__ m1,
                             const float* __restrict__ v1, ushort_t* __restrict__ h, int N) {
    int ln = threadIdx.x >> 7;     // 0..1 (2 nodes per 256-block)
    int c  = threadIdx.x & 127;
    int n  = blockIdx.x * 2 + ln;
    if (n >= N) return;
    float acc = 0.f;
#pragma unroll
    for (int k = 0; k < 6; k++) acc += aggx[(size_t)n * 6 + k] * W1[k * HID + c];
    float s = rsqrtf(v1[c] + EPS);
    float A = g1[c] * s;
    float C = (b1[c] - m1[c]) * A + be1[c];
    float r = acc * A + C;
    h[(size_t)n * HID + c] = f2bf_rne(r > 0.f ? r : 0.f);
}

// ---------------- 128-wide aggregation: one wave per node (R8 structure),
// wave-uniform scalarized metadata: n via readfirstlane -> colptr/dinv/swsrcs
// loads become SMEM s_load; row gathers remain per-lane vector loads.

__global__ __launch_bounds__(256) void agg_kernel(
    const ushort_t* __restrict__ h, const float* __restrict__ dinv,
    const int* __restrict__ colptr, const int2* __restrict__ swsrcs,
    ushort_t* __restrict__ aggb, int N) {
    int lane = threadIdx.x & 63;
    int n = __builtin_amdgcn_readfirstlane(blockIdx.x * 4 + (threadIdx.x >> 6));
    if (n >= N) return;
    float dn = dinv[n];
    const uint_t* hv = (const uint_t*)h;  // row = 64 uints (128 bf16)
    float ax, ay;
    {
        uint_t hs = hv[(size_t)n * 64 + lane];
        float sw = dn * dn;
        ax = bf2f_lo(hs) * sw;
        ay = bf2f_hi(hs) * sw;
    }
    int s0 = colptr[n], s1 = colptr[n + 1];
    int j = s0;
    for (; j + 8 <= s1; j += 8) {                 // full-rate unmasked main loop
        int2 sv[8];
#pragma unroll
        for (int u = 0; u < 8; u++) sv[u] = swsrcs[j + u];
        uint_t hh[8];
#pragma unroll
        for (int u = 0; u < 8; u++) hh[u] = hv[(size_t)sv[u].x * 64 + lane];
#pragma unroll
        for (int u = 0; u < 8; u++) {
            float w = __int_as_float(sv[u].y) * dn;
            ax += bf2f_lo(hh[u]) * w;
            ay += bf2f_hi(hh[u]) * w;
        }
    }
    if (j < s1) {                                  // single masked group for remainder
        int2 sv[8];
#pragma unroll
        for (int u = 0; u < 8; u++) {
            int idx = (j + u < s1) ? (j + u) : (s1 - 1);
            sv[u] = swsrcs[idx];
        }
        uint_t hh[8];
#pragma unroll
        for (int u = 0; u < 8; u++) hh[u] = hv[(size_t)sv[u].x * 64 + lane];
#pragma unroll
        for (int u = 0; u < 8; u++) {
            float w = (j + u < s1) ? __int_as_float(sv[u].y) * dn : 0.f;
            ax += bf2f_lo(hh[u]) * w;
            ay += bf2f_hi(hh[u]) * w;
        }
    }
    uint_t o = (uint_t)f2bf_rne(ax) | ((uint_t)f2bf_rne(ay) << 16);
    ((uint_t*)aggb)[(size_t)n * 64 + lane] = o;
}

// ---------------- W pre-split: f32 [in][out] -> swizzled bf16 hi||lo (both layers) ----------------

__global__ void wprep_kernel(const float* __restrict__ W2, const float* __restrict__ W3,
                             ushort_t* __restrict__ Wsw2, ushort_t* __restrict__ Wsw3) {
    int bb = blockIdx.x;
    const float* W = (bb < 64) ? W2 : W3;
    ushort_t* Wsw = (bb < 64) ? Wsw2 : Wsw3;
    int idx = (bb & 63) * 256 + threadIdx.x;    // 64 blocks x 256 = 16384 per layer
    int k = idx >> 7;        // in
    int o = idx & 127;       // out
    float w = W[idx];        // W[k][o]
    unsigned u = __float_as_uint(w);
    ushort_t hw = (ushort_t)(u >> 16);                       // truncated bf16 (hi)
    float hf = __uint_as_float(u & 0xffff0000u);
    float lo = w - hf;
    ushort_t lw = (ushort_t)(__float_as_uint(lo) >> 16);     // truncated bf16 (lo)
    int chunk = k >> 3, j = k & 7;
    int sidx = o * 128 + ((chunk ^ (o & 7)) << 3) + j;
    Wsw[sidx] = hw;
    Wsw[16384 + sidx] = lw;
}

// ---------------- BN coef precompute (both layers) ----------------

__global__ void bnprep_kernel(const float* __restrict__ b2, const float* __restrict__ g2,
                              const float* __restrict__ be2, const float* __restrict__ m2,
                              const float* __restrict__ v2, float* __restrict__ cA2,
                              float* __restrict__ cC2,
                              const float* __restrict__ b3, const float* __restrict__ g3,
                              const float* __restrict__ be3, const float* __restrict__ m3,
                              const float* __restrict__ v3, float* __restrict__ cA3,
                              float* __restrict__ cC3) {
    int c = threadIdx.x;
    const float* b = blockIdx.x ? b3 : b2;
    const float* g = blockIdx.x ? g3 : g2;
    const float* be = blockIdx.x ? be3 : be2;
    const float* m = blockIdx.x ? m3 : m2;
    const float* v = blockIdx.x ? v3 : v2;
    float* cA = blockIdx.x ? cA3 : cA2;
    float* cC = blockIdx.x ? cC3 : cC2;
    float A = g[c] * rsqrtf(v[c] + EPS);
    cA[c] = A;
    cC[c] = (b[c] - m[c]) * A + be[c];
}

// ---------------- MFMA GEMM: bf16 A x (Wh+Wl) + BN + ReLU (+ fused pool) ----------------

template <bool POOL>
__global__ __launch_bounds__(256, 2) void gemm_mfma_kernel(
    const ushort_t* __restrict__ aggb,    // [N][128] bf16
    const ushort_t* __restrict__ Wsw,     // swizzled hi||lo, 64 KB
    const float* __restrict__ cA,         // [128] BN scale
    const float* __restrict__ cC,         // [128] BN shift
    ushort_t* __restrict__ out_h,         // non-pool: bf16 h out
    float* __restrict__ out_pool,         // pool: f32 accum out
    const int* __restrict__ batch, int N) {
    __shared__ unsigned smu[16384];       // 64 KB: W(hi|lo) during K-loop, f32 tile in epilogue
    ushort_t* Wh = (ushort_t*)smu;
    ushort_t* Wl = (ushort_t*)smu + 16384;
    float* At = (float*)smu;

    int tid  = threadIdx.x;
    int wid  = tid >> 6;           // wave 0..3
    int lane = tid & 63;
    int l15  = lane & 15;
    int lg   = lane >> 4;          // 0..3

    int nbase = blockIdx.x * 128;
    int rbase = nbase + wid * 32;
    int r0c = min(rbase + l15, N - 1);
    int r1c = min(rbase + 16 + l15, N - 1);

    // stage W into LDS via direct global->LDS DMA (linear layout, pre-swizzled in global)
    {
        const char* g = (const char*)Wsw;
        char* l = (char*)smu;
        int wbase = (tid & ~63) << 4;      // wave-uniform LDS base within each 4KB chunk
#pragma unroll
        for (int i = 0; i < 16; i++) {
            gload_lds16(g + i * 4096 + tid * 16, l + i * 4096 + wbase);
        }
    }

    // BN coefs for this lane's 8 output channels (overlaps with DMA)
    float kA[8], kC[8];
#pragma unroll
    for (int cb = 0; cb < 8; cb++) {
        int n = cb * 16 + l15;
        kA[cb] = cA[n];
        kC[cb] = cC[n];
    }
    __syncthreads();

    float4v acc[2][8];
#pragma unroll
    for (int h = 0; h < 2; h++)
#pragma unroll
        for (int cb = 0; cb < 8; cb++) acc[h][cb] = (float4v){0.f, 0.f, 0.f, 0.f};

#pragma unroll
    for (int kk = 0; kk < 4; kk++) {
        int ko = kk * 32 + lg * 8;             // 8 consecutive k per lane
        short8v Ah0 = *(const short8v*)(aggb + (size_t)r0c * HID + ko);
        short8v Ah1 = *(const short8v*)(aggb + (size_t)r1c * HID + ko);
        int chunk = kk * 4 + lg;
#pragma unroll
        for (int cb = 0; cb < 8; cb++) {
            int n = cb * 16 + l15;
            int sidx = n * 128 + ((chunk ^ (n & 7)) << 3);
            short8v bh = *(const short8v*)(Wh + sidx);
            short8v bl = *(const short8v*)(Wl + sidx);
            acc[0][cb] = __builtin_amdgcn_mfma_f32_16x16x32_bf16(Ah0, bh, acc[0][cb], 0, 0, 0);
            acc[1][cb] = __builtin_amdgcn_mfma_f32_16x16x32_bf16(Ah1, bh, acc[1][cb], 0, 0, 0);
            acc[0][cb] = __builtin_amdgcn_mfma_f32_16x16x32_bf16(Ah0, bl, acc[0][cb], 0, 0, 0);
            acc[1][cb] = __builtin_amdgcn_mfma_f32_16x16x32_bf16(Ah1, bl, acc[1][cb], 0, 0, 0);
        }
    }

    __syncthreads();   // all waves done reading W; reuse LDS as f32 tile

    // BN + ReLU, write acc into LDS tile [128][128] with col swizzle
#pragma unroll
    for (int h = 0; h < 2; h++) {
#pragma unroll
        for (int r = 0; r < 4; r++) {
            int lr = wid * 32 + h * 16 + lg * 4 + r;
            int swz = ((lr >> 2) & 3) << 2;
#pragma unroll
            for (int cb = 0; cb < 8; cb++) {
                int c = cb * 16 + l15;
                float val = fmaxf(acc[h][cb][r] * kA[cb] + kC[cb], 0.f);
                if (POOL && (nbase + lr) >= N) val = 0.f;
                At[lr * 128 + (c ^ swz)] = val;
            }
        }
    }
    __syncthreads();

    if (!POOL) {
        // coalesced bf16 row writes: 16 threads x 8ch cover a 256B row
        int c8 = tid & 15;           // 8-channel chunk
        int rb = tid >> 4;           // 16 rows per pass
#pragma unroll
        for (int i = 0; i < 8; i++) {
            int r = rb + i * 16;
            int gr = nbase + r;
            if (gr < N) {
                int swz = ((r >> 2) & 3) << 2;
                float4 va = *(float4*)&At[r * 128 + ((c8 * 8) ^ swz)];
                float4 vb = *(float4*)&At[r * 128 + ((c8 * 8 + 4) ^ swz)];
                ushort8v o;
                o[0] = f2bf_rne(va.x); o[1] = f2bf_rne(va.y);
                o[2] = f2bf_rne(va.z); o[3] = f2bf_rne(va.w);
                o[4] = f2bf_rne(vb.x); o[5] = f2bf_rne(vb.y);
                o[6] = f2bf_rne(vb.z); o[7] = f2bf_rne(vb.w);
                *(ushort8v*)&out_h[(size_t)gr * HID + c8 * 8] = o;
            }
        }
    } else {
        // segmented pool reduction: batch is sorted, few segments per block
        int c  = tid & 127;
        int rh = tid >> 7;          // 0..1, rows rh*64 .. rh*64+63
        int r0 = rh * 64;
        int cg = batch[min(nbase + r0, N - 1)];
        float racc = 0.f;
        for (int r = r0; r < r0 + 64; r++) {
            int gr = min(nbase + r, N - 1);
            int g = batch[gr];
            float vv = At[r * 128 + (c ^ (((r >> 2) & 3) << 2))];
            if (g != cg) {
                atomicAdd(&out_pool[(size_t)cg * HID + c], racc);
                racc = 0.f;
                cg = g;
            }
            racc += vv;
        }
        atomicAdd(&out_pool[(size_t)cg * HID + c], racc);
    }
}

// ---------------- pooling finalize ----------------

__global__ void finalize_kernel(float* __restrict__ out, const int* __restrict__ gcnt, int total) {
    int i = blockIdx.x * blockDim.x + threadIdx.x;
    if (i < total) {
        int gidx = i >> 7;
        out[i] = out[i] / fmaxf((float)gcnt[gidx], 1.f);
    }
}

// ---------------- launch ----------------

extern "C" void kernel_launch(void* const* d_in, const int* in_sizes, int n_in,
                              void* d_out, int out_size, void* d_ws, size_t ws_size,
                              hipStream_t stream) {
    const float* x   = (const float*)d_in[0];
    const int*  ei   = (const int*)d_in[1];
    const int*  batch= (const int*)d_in[3];
    const float* W1  = (const float*)d_in[4];
    const float* b1  = (const float*)d_in[5];
    const float* W2  = (const float*)d_in[6];
    const float* b2  = (const float*)d_in[7];
    const float* W3  = (const float*)d_in[8];
    const float* b3  = (const float*)d_in[9];
    const float* g1  = (const float*)d_in[10];
    const float* be1 = (const float*)d_in[11];
    const float* m1  = (const float*)d_in[12];
    const float* v1  = (const float*)d_in[13];
    const float* g2  = (const float*)d_in[14];
    const float* be2 = (const float*)d_in[15];
    const float* m2  = (const float*)d_in[16];
    const float* v2  = (const float*)d_in[17];
    const float* g3  = (const float*)d_in[18];
    const float* be3 = (const float*)d_in[19];
    const float* m3  = (const float*)d_in[20];
    const float* v3  = (const float*)d_in[21];

    const int N  = in_sizes[0] / 6;
    const int E  = in_sizes[1] / 2;
    const int NG = out_size / HID;
    const int* row = ei;
    const int* col = ei + E;
    const int NBKT = (N + 255) >> BSH;        // 391 for N=100000 (<=512 supported)

    char* wp = (char*)d_ws;
    auto alloc = [&](size_t bytes) -> void* {
        void* p = (void*)wp;
        wp += (bytes + 255) & ~(size_t)255;
        return p;
    };
    // bkthist and gcnt allocated adjacently -> single memset covers both
    int*   bkthist = (int*)alloc((size_t)(NBKT + 1) * 4);
    int*   gcnt    = (int*)alloc((size_t)NG * 4);
    size_t zspan   = (size_t)((char*)gcnt + (size_t)NG * 4 - (char*)bkthist);
    float* dinv    = (float*)alloc((size_t)N * 4);
    int*   cnt     = (int*)alloc((size_t)N * 4);
    int*   colptr  = (int*)alloc(((size_t)N + 1) * 4);
    const int NB1 = (N + 1023) / 1024;
    int*   bsum    = (int*)alloc((size_t)NB1 * 4);
    int*   bktbase = (int*)alloc((size_t)(NBKT + 1) * 4);
    int*   bktcur  = (int*)alloc((size_t)(NBKT + 1) * 4);
    uint_t* epart  = (uint_t*)alloc((size_t)E * 4);
    int2*  swsrcs  = (int2*)alloc((size_t)E * 8);
    float* aggx    = (float*)alloc((size_t)N * 6 * 4);
    ushort_t* aggb = (ushort_t*)alloc((size_t)N * HID * 2);
    ushort_t* h    = (ushort_t*)alloc((size_t)N * HID * 2);
    ushort_t* Wsw2 = (ushort_t*)alloc((size_t)2 * HID * HID * 2);
    ushort_t* Wsw3 = (ushort_t*)alloc((size_t)2 * HID * HID * 2);
    float* cA2 = (float*)alloc(HID * 4);
    float* cC2 = (float*)alloc(HID * 4);
    float* cA3 = (float*)alloc(HID * 4);
    float* cC3 = (float*)alloc(HID * 4);
    float* outf   = (float*)d_out;

    hipMemsetAsync(bkthist, 0, zspan, stream);
    hipMemsetAsync(d_out, 0, (size_t)out_size * 4, stream);

    const int B = 256;
    // weight/BN precompute (tiny)
    wprep_kernel<<<128, 256, 0, stream>>>(W2, W3, Wsw2, Wsw3);
    bnprep_kernel<<<2, 128, 0, stream>>>(b2, g2, be2, m2, v2, cA2, cC2,
                                         b3, g3, be3, m3, v3, cA3, cC3);

    // bucketed CSR build
    const int HB = 512;
    const int hchunk = (E + HB - 1) / HB;
    hist_kernel<<<HB, B, 0, stream>>>(col, E, hchunk, bkthist, NBKT);
    bktscan_kernel<<<1, 512, 0, stream>>>(bkthist, bktbase, bktcur, NBKT);
    const int PB = 256;
    const int pchunk = (E + PB - 1) / PB;
    part_kernel<<<PB, B, 0, stream>>>(row, col, bktcur, epart, E, pchunk, NBKT);
    count_kernel<<<NBKT, B, 0, stream>>>(epart, bktbase, cnt, dinv, batch, gcnt, N);
    scan1_kernel<<<NB1, 1024, 0, stream>>>(cnt, colptr, bsum, N);
    scan2_kernel<<<1, 128, 0, stream>>>(bsum, NB1);
    scan3_kernel<<<(N + B - 1) / B, B, 0, stream>>>(colptr, bsum, N);
    place_kernel<<<NBKT, B, 0, stream>>>(epart, bktbase, colptr, dinv, swsrcs);

    // layer 1 (aggregate x first: only 6 channels)
    aggx_kernel<<<(N + 31) / 32, B, 0, stream>>>(x, dinv, colptr, swsrcs, aggx, N);
    gemm1_kernel<<<(N + 1) / 2, B, 0, stream>>>(aggx, W1, b1, g1, be1, m1, v1, h, N);

    const int NBLK = (N + 127) / 128;
    // layer 2
    agg_kernel<<<(N + 3) / 4, B, 0, stream>>>(h, dinv, colptr, swsrcs, aggb, N);
    gemm_mfma_kernel<false><<<NBLK, 256, 0, stream>>>(aggb, Wsw2, cA2, cC2, h, nullptr, nullptr, N);

    // layer 3 (+ fused mean-pool accumulate)
    agg_kernel<<<(N + 3) / 4, B, 0, stream>>>(h, dinv, colptr, swsrcs, aggb, N);
    gemm_mfma_kernel<true><<<NBLK, 256, 0, stream>>>(aggb, Wsw3, cA3, cC3, nullptr, outf, batch, N);

    finalize_kernel<<<(NG * HID + B - 1) / B, B, 0, stream>>>(outf, gcnt, NG * HID);
}